// Round 7
// baseline (678.799 us; speedup 1.0000x reference)
//
#include <hip/hip_runtime.h>
#include <stdint.h>

typedef unsigned short ushort_t;
typedef __bf16 bf16_t;
typedef bf16_t bf16x8 __attribute__((ext_vector_type(8)));
typedef float f32x4 __attribute__((ext_vector_type(4)));

#define H_ 256
#define W_ 256
#define C_ 128
#define EPSV 1.001e-05f
#define QSCALE 0.17677669529663687f

// d_ws layout (bytes)
#define WSO_QKVW 0u         // ushort[24*4*512]  = 98304 B
#define WSO_PROJW 98304u    // ushort[8*4*512]   = 32768 B
#define WSO_W1   131072u    // ushort[32*4*512]  = 131072 B
#define WSO_W2   262144u    // ushort[8*16*512]  = 131072 B
#define WSO_BIAS 393216u    // bf16 [4][64][64]  = 32768 B

__device__ __forceinline__ ushort_t f2bf(float f) {
  unsigned int u = __float_as_uint(f);
  u += 0x7fffu + ((u >> 16) & 1u);   // RNE
  return (ushort_t)(u >> 16);
}
__device__ __forceinline__ float bf2f(ushort_t u) {
  return __uint_as_float(((unsigned int)u) << 16);
}
__device__ __forceinline__ unsigned int pk2(float a, float b) {
  return (unsigned)f2bf(a) | ((unsigned)f2bf(b) << 16);
}
// rowB-stride bf16 tile, XOR-swizzled with (row&7)<<4  (rowB >= 128)
__device__ __forceinline__ bf16x8 ldfrag(const char* base, int rowB, int row, int col) {
  int off = row * rowB + ((col * 2) ^ ((row & 7) << 4));
  return *reinterpret_cast<const bf16x8*>(base + off);
}
__device__ __forceinline__ void stbf(char* base, int rowB, int row, int col, float v) {
  int off = row * rowB + ((col * 2) ^ ((row & 7) << 4));
  *reinterpret_cast<ushort_t*>(base + off) = f2bf(v);
}
// [64][32] bf16 slice, rowB=64, XOR (row&3)<<4 (bijective within 64B row)
__device__ __forceinline__ bf16x8 ldfrag64(const char* base, int row, int col) {
  int off = row * 64 + ((col * 2) ^ ((row & 3) << 4));
  return *reinterpret_cast<const bf16x8*>(base + off);
}
__device__ __forceinline__ void stbf64(char* base, int row, int col, float v) {
  int off = row * 64 + ((col * 2) ^ ((row & 3) << 4));
  *reinterpret_cast<ushort_t*>(base + off) = f2bf(v);
}
// fast GELU (tanh form)
__device__ __forceinline__ float gelu_f(float v) {
  float u = v * v;
  float z = v * fmaf(0.0713548162726f, u, 1.59576912161f);
  float e = __expf(z);
  float r = __builtin_amdgcn_rcpf(e + 1.0f);
  return v - v * r;
}

// ---------------- prep: weights -> bf16 fragment-major, bias table ----------------
__global__ __launch_bounds__(256)
void prep_k(const float* __restrict__ qkvw, const float* __restrict__ projw,
            const float* __restrict__ w1, const float* __restrict__ w2,
            const float* __restrict__ rpb, char* __restrict__ ws)
{
  int idx = blockIdx.x * 256 + threadIdx.x;   // grid 832 -> 212992 exact
  if (idx < 49152) {                          // qkvw frags: 24 ntiles x 4 ks
    int t = idx >> 9, r = idx & 511; int l = r >> 3, j = r & 7;
    int gn = t >> 2, ks = t & 3;
    int k = ks*32 + (l>>4)*8 + j, n = gn*16 + (l&15);
    ((ushort_t*)(ws + WSO_QKVW))[idx] = f2bf(qkvw[k*384 + n]);
  } else if (idx < 65536) {                   // projw: 8 x 4
    int i = idx - 49152;
    int t = i >> 9, r = i & 511; int l = r >> 3, j = r & 7;
    int gn = t >> 2, ks = t & 3;
    int k = ks*32 + (l>>4)*8 + j, n = gn*16 + (l&15);
    ((ushort_t*)(ws + WSO_PROJW))[i] = f2bf(projw[k*128 + n]);
  } else if (idx < 131072) {                  // w1: 32 x 4
    int i = idx - 65536;
    int t = i >> 9, r = i & 511; int l = r >> 3, j = r & 7;
    int gn = t >> 2, ks = t & 3;
    int k = ks*32 + (l>>4)*8 + j, n = gn*16 + (l&15);
    ((ushort_t*)(ws + WSO_W1))[i] = f2bf(w1[k*512 + n]);
  } else if (idx < 196608) {                  // w2: 8 ntiles x 16 ks
    int i = idx - 131072;
    int t = i >> 9, r = i & 511; int l = r >> 3, j = r & 7;
    int gn = t >> 4, ks = t & 15;
    int k = ks*32 + (l>>4)*8 + j, n = gn*16 + (l&15);
    ((ushort_t*)(ws + WSO_W2))[i] = f2bf(w2[k*128 + n]);
  } else {                                    // bias table bf16 [4][64][64]
    int i = idx - 196608;
    int h = i >> 12, ij = i & 4095, ti = ij >> 6, tj = ij & 63;
    int rel = ((ti>>3) - (tj>>3) + 7)*15 + ((ti&7) - (tj&7) + 7);
    ((ushort_t*)(ws + WSO_BIAS))[i] = f2bf(rpb[rel*4 + h]);
  }
}

// ---------------- fused block kernel, 48.5 KB LDS -> 3 blocks/CU ----------------
// R0 [0,16K):   xw -> vT slices (h*4K) -> O tile -> hsm
// R1 [16K,32K): q slices (h*4K) -> P.lo slices -> y tile (bf16)
// R2 [32K,48K): k slices (h*4K) -> P.hi slices -> a tile
__global__ __launch_bounds__(256, 3)
void swin_blk_k(const float* __restrict__ x,
                const float* __restrict__ g1, const float* __restrict__ be1,
                const float* __restrict__ qkvb, const float* __restrict__ projb,
                const float* __restrict__ g2, const float* __restrict__ be2,
                const float* __restrict__ b1, const float* __restrict__ b2,
                const char* __restrict__ ws, float* __restrict__ out)
{
  __shared__ __align__(16) char smem[49152];
  __shared__ int rowoff[64];
  __shared__ int lab[64];
  char* R0 = smem;
  char* R1 = smem + 16384;
  char* R2 = smem + 32768;

  const ushort_t* qkvw_f  = (const ushort_t*)(ws + WSO_QKVW);
  const ushort_t* projw_f = (const ushort_t*)(ws + WSO_PROJW);
  const ushort_t* w1_f    = (const ushort_t*)(ws + WSO_W1);
  const ushort_t* w2_f    = (const ushort_t*)(ws + WSO_W2);
  const ushort_t* biasT   = (const ushort_t*)(ws + WSO_BIAS);

  const int tid = threadIdx.x, lane = tid & 63, wave = tid >> 6;
  const int l15 = lane & 15, lg = lane >> 4;
  const int blk = blockIdx.x;
  const int b = blk >> 10, w = blk & 1023;
  const int wh = w >> 5, ww = w & 31;

  if (tid < 64) {
    int th = tid >> 3, tw = tid & 7;
    int shh = wh*8 + th, shw = ww*8 + tw;
    int oh = (shh + 4) & (H_-1), ow = (shw + 4) & (W_-1);
    rowoff[tid] = ((b*H_ + oh)*W_ + ow) * C_;
    int hb = (shh < H_-8) ? 0 : ((shh < H_-4) ? 1 : 2);
    int wb = (shw < W_-8) ? 0 : ((shw < W_-4) ? 1 : 2);
    lab[tid] = hb*3 + wb;
  }

  { // ---- P1: LN1 -> xw (R0) ----
    int t = tid >> 2, p = tid & 3;
    int th = t >> 3, tw = t & 7;
    int oh = (wh*8 + th + 4) & (H_-1), ow = (ww*8 + tw + 4) & (W_-1);
    const float* xr = x + ((b*H_ + oh)*W_ + ow)*C_ + p*32;
    float xv[32];
    #pragma unroll
    for (int c = 0; c < 8; ++c) *reinterpret_cast<float4*>(xv + c*4) = reinterpret_cast<const float4*>(xr)[c];
    float s = 0.f, s2 = 0.f;
    #pragma unroll
    for (int c = 0; c < 32; ++c) { s += xv[c]; s2 += xv[c]*xv[c]; }
    s += __shfl_xor(s, 1);  s += __shfl_xor(s, 2);
    s2 += __shfl_xor(s2, 1); s2 += __shfl_xor(s2, 2);
    float mean = s*(1.f/128.f), var = s2*(1.f/128.f) - mean*mean;
    float rs = rsqrtf(var + EPSV);
    #pragma unroll
    for (int c8 = 0; c8 < 4; ++c8) {
      float gv[8], bv[8];
      *reinterpret_cast<float4*>(gv)   = reinterpret_cast<const float4*>(g1  + p*32 + c8*8)[0];
      *reinterpret_cast<float4*>(gv+4) = reinterpret_cast<const float4*>(g1  + p*32 + c8*8)[1];
      *reinterpret_cast<float4*>(bv)   = reinterpret_cast<const float4*>(be1 + p*32 + c8*8)[0];
      *reinterpret_cast<float4*>(bv+4) = reinterpret_cast<const float4*>(be1 + p*32 + c8*8)[1];
      float nv[8];
      #pragma unroll
      for (int j = 0; j < 8; ++j) nv[j] = (xv[c8*8+j] - mean)*rs*gv[j] + bv[j];
      uint4 pkv;
      pkv.x = pk2(nv[0],nv[1]); pkv.y = pk2(nv[2],nv[3]);
      pkv.z = pk2(nv[4],nv[5]); pkv.w = pk2(nv[6],nv[7]);
      int off = t*256 + ((p*64 + c8*16) ^ ((t&7) << 4));
      *reinterpret_cast<uint4*>(R0 + off) = pkv;
    }
  }
  __syncthreads();   // B1: xw ready

  bf16x8 afr[4][4];
  #pragma unroll
  for (int mi = 0; mi < 4; ++mi)
    #pragma unroll
    for (int ks = 0; ks < 4; ++ks)
      afr[mi][ks] = ldfrag(R0, 256, l15 + mi*16, ks*32 + lg*8);
  __syncthreads();   // B2: all afr loads done -> R0 reusable

  char* qsl = R1 + wave*4096;   // own head's [64][32] slices
  char* ksl = R2 + wave*4096;
  char* vsl = R0 + wave*4096;   // vT [32][64] rowB=128

  { // ---- P2: q,k,v GEMMs for own head (barrier-free) ----
    #pragma unroll
    for (int gg = 0; gg < 2; ++gg) {   // q tiles 2w+gg
      int gn = 2*wave + gg;
      f32x4 acc[4] = {{0,0,0,0},{0,0,0,0},{0,0,0,0},{0,0,0,0}};
      #pragma unroll
      for (int ks = 0; ks < 4; ++ks) {
        bf16x8 bf = *reinterpret_cast<const bf16x8*>(qkvw_f + (size_t)(gn*4 + ks)*512 + lane*8);
        #pragma unroll
        for (int mi = 0; mi < 4; ++mi)
          acc[mi] = __builtin_amdgcn_mfma_f32_16x16x32_bf16(afr[mi][ks], bf, acc[mi], 0, 0, 0);
      }
      float bv = qkvb[gn*16 + l15];
      #pragma unroll
      for (int mi = 0; mi < 4; ++mi)
        #pragma unroll
        for (int rr = 0; rr < 4; ++rr)
          stbf64(qsl, mi*16 + lg*4 + rr, gg*16 + l15, (acc[mi][rr] + bv)*QSCALE);
    }
    #pragma unroll
    for (int gg = 0; gg < 2; ++gg) {   // k tiles 8+2w+gg
      int gn = 8 + 2*wave + gg;
      f32x4 acc[4] = {{0,0,0,0},{0,0,0,0},{0,0,0,0},{0,0,0,0}};
      #pragma unroll
      for (int ks = 0; ks < 4; ++ks) {
        bf16x8 bf = *reinterpret_cast<const bf16x8*>(qkvw_f + (size_t)(gn*4 + ks)*512 + lane*8);
        #pragma unroll
        for (int mi = 0; mi < 4; ++mi)
          acc[mi] = __builtin_amdgcn_mfma_f32_16x16x32_bf16(afr[mi][ks], bf, acc[mi], 0, 0, 0);
      }
      float bv = qkvb[128 + (gn-8)*16 + l15];
      #pragma unroll
      for (int mi = 0; mi < 4; ++mi)
        #pragma unroll
        for (int rr = 0; rr < 4; ++rr)
          stbf64(ksl, mi*16 + lg*4 + rr, gg*16 + l15, acc[mi][rr] + bv);
    }
    #pragma unroll
    for (int gg = 0; gg < 2; ++gg) {   // v tiles 16+2w+gg -> vT [d_local][tok]
      int gn = 16 + 2*wave + gg;
      f32x4 acc[4] = {{0,0,0,0},{0,0,0,0},{0,0,0,0},{0,0,0,0}};
      #pragma unroll
      for (int ks = 0; ks < 4; ++ks) {
        bf16x8 bf = *reinterpret_cast<const bf16x8*>(qkvw_f + (size_t)(gn*4 + ks)*512 + lane*8);
        #pragma unroll
        for (int mi = 0; mi < 4; ++mi)
          acc[mi] = __builtin_amdgcn_mfma_f32_16x16x32_bf16(afr[mi][ks], bf, acc[mi], 0, 0, 0);
      }
      float bv = qkvb[256 + (gn-16)*16 + l15];
      #pragma unroll
      for (int mi = 0; mi < 4; ++mi)
        #pragma unroll
        for (int rr = 0; rr < 4; ++rr)
          stbf(vsl, 128, gg*16 + l15, mi*16 + lg*4 + rr, acc[mi][rr] + bv);
    }
  }

  { // ---- P3: QK^T + softmax + P + PV + O (barrier-free until B3) ----
    bf16x8 qa[4], kb[4];
    #pragma unroll
    for (int mi = 0; mi < 4; ++mi) qa[mi] = ldfrag64(qsl, l15 + mi*16, lg*8);
    #pragma unroll
    for (int ni = 0; ni < 4; ++ni) kb[ni] = ldfrag64(ksl, l15 + ni*16, lg*8);
    f32x4 S[4][4];
    #pragma unroll
    for (int mi = 0; mi < 4; ++mi)
      #pragma unroll
      for (int ni = 0; ni < 4; ++ni) {
        f32x4 z = {0,0,0,0};
        S[mi][ni] = __builtin_amdgcn_mfma_f32_16x16x32_bf16(qa[mi], kb[ni], z, 0, 0, 0);
      }
    int labC[4];
    #pragma unroll
    for (int ni = 0; ni < 4; ++ni) labC[ni] = lab[ni*16 + l15];
    float rinv[4][4];
    #pragma unroll
    for (int mi = 0; mi < 4; ++mi)
      #pragma unroll
      for (int rr = 0; rr < 4; ++rr) {
        int row = mi*16 + lg*4 + rr;
        int labR = lab[row];
        const ushort_t* bp = biasT + wave*4096 + row*64 + l15;
        #pragma unroll
        for (int ni = 0; ni < 4; ++ni)
          S[mi][ni][rr] += bf2f(bp[ni*16]) + ((labC[ni] == labR) ? 0.f : -100.f);
        float mx = fmaxf(fmaxf(S[mi][0][rr], S[mi][1][rr]), fmaxf(S[mi][2][rr], S[mi][3][rr]));
        mx = fmaxf(mx, __shfl_xor(mx, 1)); mx = fmaxf(mx, __shfl_xor(mx, 2));
        mx = fmaxf(mx, __shfl_xor(mx, 4)); mx = fmaxf(mx, __shfl_xor(mx, 8));
        float sum = 0.f;
        #pragma unroll
        for (int ni = 0; ni < 4; ++ni) {
          float e = __expf(S[mi][ni][rr] - mx);
          S[mi][ni][rr] = e; sum += e;
        }
        sum += __shfl_xor(sum, 1); sum += __shfl_xor(sum, 2);
        sum += __shfl_xor(sum, 4); sum += __shfl_xor(sum, 8);
        rinv[mi][rr] = __builtin_amdgcn_rcpf(sum);
      }
    // P: lo half -> own q slice, hi half -> own k slice (both dead)
    #pragma unroll
    for (int mi = 0; mi < 4; ++mi)
      #pragma unroll
      for (int ni = 0; ni < 4; ++ni)
        #pragma unroll
        for (int rr = 0; rr < 4; ++rr) {
          char* dst = (ni < 2) ? qsl : ksl;
          stbf64(dst, mi*16 + lg*4 + rr, (ni & 1)*16 + l15, S[mi][ni][rr]);
        }
    // PV
    f32x4 O[4][2] = {{{0,0,0,0},{0,0,0,0}},{{0,0,0,0},{0,0,0,0}},
                     {{0,0,0,0},{0,0,0,0}},{{0,0,0,0},{0,0,0,0}}};
    #pragma unroll
    for (int ks = 0; ks < 2; ++ks) {
      char* psrc = (ks == 0) ? qsl : ksl;
      bf16x8 pa[4];
      #pragma unroll
      for (int mi = 0; mi < 4; ++mi) pa[mi] = ldfrag64(psrc, l15 + mi*16, lg*8);
      #pragma unroll
      for (int ni = 0; ni < 2; ++ni) {
        bf16x8 vb = ldfrag(vsl, 128, ni*16 + l15, ks*32 + lg*8);
        #pragma unroll
        for (int mi = 0; mi < 4; ++mi)
          O[mi][ni] = __builtin_amdgcn_mfma_f32_16x16x32_bf16(pa[mi], vb, O[mi][ni], 0, 0, 0);
      }
    }
    __syncthreads();   // B3: everyone done with vT/P -> O tile may claim R0
    #pragma unroll
    for (int mi = 0; mi < 4; ++mi)
      #pragma unroll
      for (int ni = 0; ni < 2; ++ni)
        #pragma unroll
        for (int rr = 0; rr < 4; ++rr)
          stbf(R0, 256, mi*16 + lg*4 + rr, wave*32 + ni*16 + l15, O[mi][ni][rr]*rinv[mi][rr]);
  }
  __syncthreads();   // B4: O ready

  { // ---- P4: proj + x residual -> y (bf16, R1) ----
    bf16x8 oa[4][4];
    #pragma unroll
    for (int mi = 0; mi < 4; ++mi)
      #pragma unroll
      for (int ks = 0; ks < 4; ++ks)
        oa[mi][ks] = ldfrag(R0, 256, l15 + mi*16, ks*32 + lg*8);
    #pragma unroll
    for (int g = 0; g < 2; ++g) {
      int gn = wave*2 + g;
      f32x4 acc[4] = {{0,0,0,0},{0,0,0,0},{0,0,0,0},{0,0,0,0}};
      #pragma unroll
      for (int ks = 0; ks < 4; ++ks) {
        bf16x8 bf = *reinterpret_cast<const bf16x8*>(projw_f + (size_t)(gn*4 + ks)*512 + lane*8);
        #pragma unroll
        for (int mi = 0; mi < 4; ++mi)
          acc[mi] = __builtin_amdgcn_mfma_f32_16x16x32_bf16(oa[mi][ks], bf, acc[mi], 0, 0, 0);
      }
      float pbv = projb[gn*16 + l15];
      #pragma unroll
      for (int mi = 0; mi < 4; ++mi)
        #pragma unroll
        for (int rr = 0; rr < 4; ++rr) {
          int tok = mi*16 + lg*4 + rr;
          int col = gn*16 + l15;
          stbf(R1, 256, tok, col, acc[mi][rr] + pbv + x[rowoff[tok] + col]);
        }
    }
  }
  __syncthreads();   // B5: y ready (also: all O reads done -> R0 reusable)

  { // ---- P5: LN2 (y bf16) -> hsm (R0) ----
    int t = tid >> 2, p = tid & 3;
    float xv[32];
    #pragma unroll
    for (int c8 = 0; c8 < 4; ++c8) {
      int off = t*256 + ((p*64 + c8*16) ^ ((t&7) << 4));
      uint4 rv = *reinterpret_cast<const uint4*>(R1 + off);
      unsigned int uu[4] = {rv.x, rv.y, rv.z, rv.w};
      #pragma unroll
      for (int q = 0; q < 4; ++q) {
        xv[c8*8 + q*2]     = __uint_as_float(uu[q] << 16);
        xv[c8*8 + q*2 + 1] = __uint_as_float(uu[q] & 0xffff0000u);
      }
    }
    float s = 0.f, s2 = 0.f;
    #pragma unroll
    for (int c = 0; c < 32; ++c) { s += xv[c]; s2 += xv[c]*xv[c]; }
    s += __shfl_xor(s, 1);  s += __shfl_xor(s, 2);
    s2 += __shfl_xor(s2, 1); s2 += __shfl_xor(s2, 2);
    float mean = s*(1.f/128.f), var = s2*(1.f/128.f) - mean*mean;
    float rs = rsqrtf(var + EPSV);
    #pragma unroll
    for (int c8 = 0; c8 < 4; ++c8) {
      float gv[8], bv[8];
      *reinterpret_cast<float4*>(gv)   = reinterpret_cast<const float4*>(g2  + p*32 + c8*8)[0];
      *reinterpret_cast<float4*>(gv+4) = reinterpret_cast<const float4*>(g2  + p*32 + c8*8)[1];
      *reinterpret_cast<float4*>(bv)   = reinterpret_cast<const float4*>(be2 + p*32 + c8*8)[0];
      *reinterpret_cast<float4*>(bv+4) = reinterpret_cast<const float4*>(be2 + p*32 + c8*8)[1];
      float nv[8];
      #pragma unroll
      for (int j = 0; j < 8; ++j) nv[j] = (xv[c8*8+j] - mean)*rs*gv[j] + bv[j];
      uint4 pkv;
      pkv.x = pk2(nv[0],nv[1]); pkv.y = pk2(nv[2],nv[3]);
      pkv.z = pk2(nv[4],nv[5]); pkv.w = pk2(nv[6],nv[7]);
      int off = t*256 + ((p*64 + c8*16) ^ ((t&7) << 4));
      *reinterpret_cast<uint4*>(R0 + off) = pkv;
    }
  }
  __syncthreads();   // B6: hsm ready

  { // ---- P6: MLP chunked (a tile in R2) + epilogue ----
    bf16x8 hfr[4][4];
    #pragma unroll
    for (int mi = 0; mi < 4; ++mi)
      #pragma unroll
      for (int ks = 0; ks < 4; ++ks)
        hfr[mi][ks] = ldfrag(R0, 256, l15 + mi*16, ks*32 + lg*8);
    f32x4 acc2[2][4] = {{{0,0,0,0},{0,0,0,0},{0,0,0,0},{0,0,0,0}},
                        {{0,0,0,0},{0,0,0,0},{0,0,0,0},{0,0,0,0}}};
    for (int cc = 0; cc < 4; ++cc) {
      f32x4 a1[2][4];
      #pragma unroll
      for (int gg = 0; gg < 2; ++gg) {
        int gn = cc*8 + wave*2 + gg;
        #pragma unroll
        for (int mi = 0; mi < 4; ++mi) a1[gg][mi] = f32x4{0,0,0,0};
        #pragma unroll
        for (int ks = 0; ks < 4; ++ks) {
          bf16x8 bf = *reinterpret_cast<const bf16x8*>(w1_f + (size_t)(gn*4 + ks)*512 + lane*8);
          #pragma unroll
          for (int mi = 0; mi < 4; ++mi)
            a1[gg][mi] = __builtin_amdgcn_mfma_f32_16x16x32_bf16(hfr[mi][ks], bf, a1[gg][mi], 0, 0, 0);
        }
      }
      if (cc > 0) __syncthreads();   // prev chunk's a readers done
      #pragma unroll
      for (int gg = 0; gg < 2; ++gg) {
        int gn = cc*8 + wave*2 + gg;
        float b1v = b1[gn*16 + l15];
        #pragma unroll
        for (int mi = 0; mi < 4; ++mi)
          #pragma unroll
          for (int rr = 0; rr < 4; ++rr)
            stbf(R2, 256, mi*16 + lg*4 + rr, (wave*2+gg)*16 + l15, gelu_f(a1[gg][mi][rr] + b1v));
      }
      __syncthreads();   // a chunk ready
      #pragma unroll
      for (int ks2 = 0; ks2 < 4; ++ks2) {
        bf16x8 aa[4];
        #pragma unroll
        for (int mi = 0; mi < 4; ++mi) aa[mi] = ldfrag(R2, 256, l15 + mi*16, ks2*32 + lg*8);
        #pragma unroll
        for (int g = 0; g < 2; ++g) {
          int gn2 = wave*2 + g;
          bf16x8 bf = *reinterpret_cast<const bf16x8*>(w2_f + (size_t)(gn2*16 + cc*4 + ks2)*512 + lane*8);
          #pragma unroll
          for (int mi = 0; mi < 4; ++mi)
            acc2[g][mi] = __builtin_amdgcn_mfma_f32_16x16x32_bf16(aa[mi], bf, acc2[g][mi], 0, 0, 0);
        }
      }
    }
    // epilogue: out = y + mlp + b2  (y cols wave*32.. are this wave's own)
    #pragma unroll
    for (int g = 0; g < 2; ++g) {
      int gn2 = wave*2 + g;
      int col = gn2*16 + l15;
      float b2v = b2[col];
      #pragma unroll
      for (int mi = 0; mi < 4; ++mi)
        #pragma unroll
        for (int rr = 0; rr < 4; ++rr) {
          int tok = mi*16 + lg*4 + rr;
          int yoff = tok*256 + ((col*2) ^ ((tok&7) << 4));
          float yv = bf2f(*reinterpret_cast<const ushort_t*>(R1 + yoff));
          out[rowoff[tok] + col] = yv + acc2[g][mi][rr] + b2v;
        }
    }
  }
}

extern "C" void kernel_launch(void* const* d_in, const int* in_sizes, int n_in,
                              void* d_out, int out_size, void* d_ws, size_t ws_size,
                              hipStream_t stream) {
  const float* x    = (const float*)d_in[0];
  const float* g1   = (const float*)d_in[1];
  const float* be1  = (const float*)d_in[2];
  const float* qkvw = (const float*)d_in[3];
  const float* qkvb = (const float*)d_in[4];
  const float* pw   = (const float*)d_in[5];
  const float* pb   = (const float*)d_in[6];
  const float* rpb  = (const float*)d_in[7];
  const float* g2   = (const float*)d_in[8];
  const float* be2  = (const float*)d_in[9];
  const float* w1   = (const float*)d_in[10];
  const float* b1   = (const float*)d_in[11];
  const float* w2   = (const float*)d_in[12];
  const float* b2   = (const float*)d_in[13];
  float* out = (float*)d_out;
  char* ws = (char*)d_ws;

  prep_k<<<832, 256, 0, stream>>>(qkvw, pw, w1, w2, rpb, ws);
  swin_blk_k<<<4096, 256, 0, stream>>>(x, g1, be1, qkvb, pb, g2, be2, b1, b2, ws, out);
}